// Round 1
// baseline (162.428 us; speedup 1.0000x reference)
//
#include <hip/hip_runtime.h>

#define HD 128
#define LSEQ 200
#define BATCH 2048
#define NE 8
#define SWH 64

#define BM 64        // tokens per block
#define LDX 136      // padded bf16 row stride for x tile (2-way bank conflict only)
#define LDH 264      // padded bf16 row stride for hidden tile

typedef float f32x4 __attribute__((ext_vector_type(4)));
typedef __bf16 bf16x8 __attribute__((ext_vector_type(8)));

static __device__ __forceinline__ unsigned short f2bf(float f) {
    union { float f; unsigned u; } v; v.f = f;
    unsigned u = v.u;
    u += 0x7fffu + ((u >> 16) & 1u);   // round-to-nearest-even
    return (unsigned short)(u >> 16);
}

// ---------------- routing: mean(x_real) -> switch MLP -> softmax/argmax ----------------
__global__ void route_kernel(const float* __restrict__ x_real,
                             const float* __restrict__ sW1, const float* __restrict__ sb1,
                             const float* __restrict__ sW2, const float* __restrict__ sb2,
                             float* __restrict__ out_tail, int* __restrict__ ws_route) {
    __shared__ float xm[HD];
    __shared__ float h[SWH];
    __shared__ float logits[NE];
    const int t = threadIdx.x;   // 128 threads
    if (t < HD) {
        float s = 0.f;
        for (int l = 0; l < LSEQ; ++l) s += x_real[l * HD + t];
        xm[t] = s * (1.0f / LSEQ);
    }
    __syncthreads();
    if (t < SWH) {
        float s = sb1[t];
        for (int k = 0; k < HD; ++k) s += xm[k] * sW1[t * HD + k];
        h[t] = s > 0.f ? s : 0.f;
    }
    __syncthreads();
    if (t < NE) {
        float s = sb2[t];
        for (int k = 0; k < SWH; ++k) s += h[k] * sW2[t * SWH + k];
        logits[t] = s;
    }
    __syncthreads();
    if (t == 0) {
        float mx = logits[0]; int am = 0;
        for (int e = 1; e < NE; ++e) if (logits[e] > mx) { mx = logits[e]; am = e; }
        float den = 0.f;
        for (int e = 0; e < NE; ++e) den += __expf(logits[e] - mx);
        out_tail[0] = (float)am;          // route
        out_tail[1] = 1.0f / den;         // out_prob_max = exp(0)/den
        *ws_route = am;
    }
}

// ---------------- prep: build concatenated bf16 weights in workspace ----------------
// W1c [256][128]: rows 0-127 = uW1, rows 128-255 = eW1[route]
// W2c [128][256]: cols 0-127 = uW2, cols 128-255 = eW2[route]
__global__ void prep_kernel(const float* __restrict__ uW1, const float* __restrict__ ub1,
                            const float* __restrict__ uW2, const float* __restrict__ ub2,
                            const float* __restrict__ eW1, const float* __restrict__ eb1,
                            const float* __restrict__ eW2, const float* __restrict__ eb2,
                            const int* __restrict__ ws_route,
                            unsigned short* __restrict__ W1c, unsigned short* __restrict__ W2c,
                            float* __restrict__ b1c, float* __restrict__ b2s) {
    const int r = *ws_route;
    const int i = blockIdx.x * 256 + threadIdx.x;  // 0 .. 32767
    if (i < 2 * HD * HD) {
        int o = i >> 7, k = i & 127;
        float v1 = (o < HD) ? uW1[o * HD + k] : eW1[r * HD * HD + (o - HD) * HD + k];
        W1c[i] = f2bf(v1);
        int o2 = i >> 8, j = i & 255;
        float v2 = (j < HD) ? uW2[o2 * HD + j] : eW2[r * HD * HD + o2 * HD + (j - HD)];
        W2c[i] = f2bf(v2);
    }
    if (i < 2 * HD) b1c[i] = (i < HD) ? ub1[i] : eb1[r * HD + (i - HD)];
    if (i < HD)     b2s[i] = ub2[i] + eb2[r * HD + i];
}

// ---------------- main: fused 2-stage GEMM over tokens ----------------
__global__ __launch_bounds__(256, 3)
void moe_main(const float* __restrict__ x,
              const unsigned short* __restrict__ W1c, const unsigned short* __restrict__ W2c,
              const float* __restrict__ b1c, const float* __restrict__ b2s,
              float* __restrict__ out) {
    __shared__ __align__(16) unsigned short xs[BM * LDX];  // 17408 B
    __shared__ __align__(16) unsigned short hs[BM * LDH];  // 33792 B

    const int t = threadIdx.x;
    const int lane = t & 63;
    const int w = t >> 6;          // wave 0..3
    const int l16 = lane & 15;
    const int lq = lane >> 4;      // quadrant 0..3
    const size_t base = (size_t)blockIdx.x * (BM * HD);

    // ---- stage x tile (f32 -> bf16) into LDS ----
    const float4* x4 = (const float4*)(x + base);
#pragma unroll
    for (int i = 0; i < 8; ++i) {
        int idx = t + i * 256;       // 0..2047 float4 units
        int row = idx >> 5;          // 32 float4 per row
        int c4 = idx & 31;
        float4 v = x4[idx];
        ushort4 b;
        b.x = f2bf(v.x); b.y = f2bf(v.y); b.z = f2bf(v.z); b.w = f2bf(v.w);
        *(ushort4*)&xs[row * LDX + c4 * 4] = b;
    }
    __syncthreads();

    // ---- GEMM1: Hmid[64][256] = relu(X[64][128] @ W1c^T + b1c) ----
    f32x4 acc1[4][4] = {};
    const int ncb = w * 64;          // this wave's 64 columns of Hmid
    for (int ks = 0; ks < 4; ++ks) {
        const int kofs = ks * 32 + lq * 8;
        bf16x8 a[4], b[4];
#pragma unroll
        for (int mt = 0; mt < 4; ++mt)
            a[mt] = *(const bf16x8*)&xs[(mt * 16 + l16) * LDX + kofs];
#pragma unroll
        for (int nt = 0; nt < 4; ++nt)
            b[nt] = *(const bf16x8*)&W1c[(ncb + nt * 16 + l16) * HD + kofs];
#pragma unroll
        for (int mt = 0; mt < 4; ++mt)
#pragma unroll
            for (int nt = 0; nt < 4; ++nt)
                acc1[mt][nt] = __builtin_amdgcn_mfma_f32_16x16x32_bf16(
                    a[mt], b[nt], acc1[mt][nt], 0, 0, 0);
    }
    // bias + relu + store hidden to LDS (bf16)
#pragma unroll
    for (int nt = 0; nt < 4; ++nt) {
        const int col = ncb + nt * 16 + l16;
        const float bias = b1c[col];
#pragma unroll
        for (int mt = 0; mt < 4; ++mt)
#pragma unroll
            for (int r = 0; r < 4; ++r) {
                float v = acc1[mt][nt][r] + bias;
                v = v > 0.f ? v : 0.f;
                hs[(mt * 16 + lq * 4 + r) * LDH + col] = f2bf(v);
            }
    }
    __syncthreads();

    // ---- GEMM2: out[64][128] = Hmid[64][256] @ W2c^T + b2s ----
    f32x4 acc2[4][2] = {};
    const int ncb2 = w * 32;         // this wave's 32 output columns
    for (int ks = 0; ks < 8; ++ks) {
        const int kofs = ks * 32 + lq * 8;
        bf16x8 a[4], b[2];
#pragma unroll
        for (int mt = 0; mt < 4; ++mt)
            a[mt] = *(const bf16x8*)&hs[(mt * 16 + l16) * LDH + kofs];
#pragma unroll
        for (int nt = 0; nt < 2; ++nt)
            b[nt] = *(const bf16x8*)&W2c[(ncb2 + nt * 16 + l16) * 256 + kofs];
#pragma unroll
        for (int mt = 0; mt < 4; ++mt)
#pragma unroll
            for (int nt = 0; nt < 2; ++nt)
                acc2[mt][nt] = __builtin_amdgcn_mfma_f32_16x16x32_bf16(
                    a[mt], b[nt], acc2[mt][nt], 0, 0, 0);
    }
    // epilogue: bias + f32 store
    float* outp = out + base;
#pragma unroll
    for (int nt = 0; nt < 2; ++nt) {
        const int col = ncb2 + nt * 16 + l16;
        const float bias = b2s[col];
#pragma unroll
        for (int mt = 0; mt < 4; ++mt)
#pragma unroll
            for (int r = 0; r < 4; ++r)
                outp[(size_t)(mt * 16 + lq * 4 + r) * HD + col] = acc2[mt][nt][r] + bias;
    }
}

extern "C" void kernel_launch(void* const* d_in, const int* in_sizes, int n_in,
                              void* d_out, int out_size, void* d_ws, size_t ws_size,
                              hipStream_t stream) {
    const float* x      = (const float*)d_in[0];
    const float* x_real = (const float*)d_in[1];
    // d_in[2] = user_embedding (unused by reference)
    const float* uW1 = (const float*)d_in[3];
    const float* ub1 = (const float*)d_in[4];
    const float* uW2 = (const float*)d_in[5];
    const float* ub2 = (const float*)d_in[6];
    const float* eW1 = (const float*)d_in[7];
    const float* eb1 = (const float*)d_in[8];
    const float* eW2 = (const float*)d_in[9];
    const float* eb2 = (const float*)d_in[10];
    const float* sW1 = (const float*)d_in[11];
    const float* sb1 = (const float*)d_in[12];
    const float* sW2 = (const float*)d_in[13];
    const float* sb2 = (const float*)d_in[14];
    float* out = (float*)d_out;

    char* ws = (char*)d_ws;
    int* route = (int*)ws;
    unsigned short* W1c = (unsigned short*)(ws + 64);
    unsigned short* W2c = (unsigned short*)(ws + 64 + 65536);
    float* b1c = (float*)(ws + 64 + 131072);
    float* b2s = (float*)(ws + 64 + 131072 + 1024);

    route_kernel<<<1, 128, 0, stream>>>(x_real, sW1, sb1, sW2, sb2,
                                        out + (size_t)BATCH * LSEQ * HD, route);
    prep_kernel<<<128, 256, 0, stream>>>(uW1, ub1, uW2, ub2, eW1, eb1, eW2, eb2,
                                         route, W1c, W2c, b1c, b2s);
    moe_main<<<(BATCH * LSEQ) / BM, 256, 0, stream>>>(x, W1c, W2c, b1c, b2s, out);
}